// Round 4
// baseline (2238.082 us; speedup 1.0000x reference)
//
#include <hip/hip_runtime.h>
#include <cstdint>
#include <cstddef>

typedef unsigned short u16;
typedef unsigned int   u32;
typedef unsigned long long u64;
typedef __attribute__((ext_vector_type(8))) short bf16x8;   // 8 bf16 = 4 VGPRs
typedef __attribute__((ext_vector_type(4))) float f32x4;
typedef __attribute__((ext_vector_type(4))) unsigned int u32x4;
typedef __attribute__((ext_vector_type(2))) unsigned int u32x2;

typedef __attribute__((address_space(1))) const unsigned int as1c_uint;
typedef __attribute__((address_space(3))) unsigned int as3_uint;

__device__ __forceinline__ void async16(const void* g, void* l) {
  __builtin_amdgcn_global_load_lds((as1c_uint*)g, (as3_uint*)l, 16, 0, 0);
}
__device__ __forceinline__ float bf2f(u16 u) {
  return __uint_as_float(((u32)u) << 16);
}
__device__ __forceinline__ u16 f2bf(float x) {
  u32 u = __float_as_uint(x);
  u32 r = u + 0x7FFFu + ((u >> 16) & 1u);
  return (u16)(r >> 16);
}

// LDS-only barrier: orders LDS ops without draining vmcnt, so in-flight
// global prefetch loads / output stores survive the barrier (unlike
// __syncthreads, which compiles to s_waitcnt vmcnt(0) lgkmcnt(0)).
__device__ __forceinline__ void bar_lds() {
  asm volatile("s_waitcnt lgkmcnt(0)" ::: "memory");
  __builtin_amdgcn_s_barrier();
  asm volatile("" ::: "memory");
}

// ---- IC-scope ops (sc0 sc1: bypass L1+L2, serviced at the MALL / Infinity
// Cache — the cross-XCD coherence point). Exchange units are 8B
// {payload(2×bf16), step}: naturally-aligned 8B stores/loads are single-copy
// atomic, so each unit self-validates. Publisher: fire & forget (no vmcnt ack).
// Detection: packed per-role flag word (16 flags in one line — cheapest poll:
// one line per polling wave), stored WITHOUT waiting for data-store acks; the
// flag is only a trigger. Correctness comes from the wide load validating all
// 16 embedded step tags (re-loads on straggler). ----
__device__ __forceinline__ u32 ld_u32_ic(const void* p) {
  u32 v;
  asm volatile("global_load_dword %0, %1, off sc0 sc1\n\ts_waitcnt vmcnt(0)"
               : "=v"(v) : "v"(p) : "memory");
  return v;
}
__device__ __forceinline__ void st_u32_ic(void* p, u32 v) {
  asm volatile("global_store_dword %0, %1, off sc0 sc1" :: "v"(p), "v"(v) : "memory");
}
__device__ __forceinline__ void st_unit_ic(void* p, u32x2 v) {
  asm volatile("global_store_dwordx2 %0, %1, off sc0 sc1" :: "v"(p), "v"(v) : "memory");
}
__device__ __forceinline__ void ld_units_ic(const void* p,
    u32x4& a, u32x4& b, u32x4& c, u32x4& d,
    u32x4& e, u32x4& f, u32x4& g2, u32x4& h) {
  asm volatile(
      "global_load_dwordx4 %0, %8, off sc0 sc1\n\t"
      "global_load_dwordx4 %1, %8, off offset:16 sc0 sc1\n\t"
      "global_load_dwordx4 %2, %8, off offset:32 sc0 sc1\n\t"
      "global_load_dwordx4 %3, %8, off offset:48 sc0 sc1\n\t"
      "global_load_dwordx4 %4, %8, off offset:64 sc0 sc1\n\t"
      "global_load_dwordx4 %5, %8, off offset:80 sc0 sc1\n\t"
      "global_load_dwordx4 %6, %8, off offset:96 sc0 sc1\n\t"
      "global_load_dwordx4 %7, %8, off offset:112 sc0 sc1\n\t"
      "s_waitcnt vmcnt(0)"
      : "=&v"(a), "=&v"(b), "=&v"(c), "=&v"(d),
        "=&v"(e), "=&v"(f), "=&v"(g2), "=&v"(h)
      : "v"(p) : "memory");
}

// ---------------- fp32 -> bf16 convert (x) ----------------
__global__ void cvt_k(const float4* __restrict__ in, ushort4* __restrict__ out) {
  int i = blockIdx.x * 256 + threadIdx.x;
  float4 v = in[i];
  ushort4 o;
  o.x = f2bf(v.x); o.y = f2bf(v.y); o.z = f2bf(v.z); o.w = f2bf(v.w);
  out[i] = o;
}

// ---------------- transpose+convert: out[n*K+k] = bf16(in[k*N+n]) ----------------
__global__ void tr_k(const float* __restrict__ in, u16* __restrict__ out, int K, int N) {
  __shared__ u16 t[32][33];
  int bn = blockIdx.x * 32, bk = blockIdx.y * 32;
  int x = threadIdx.x, y = threadIdx.y;
#pragma unroll
  for (int i = 0; i < 32; i += 8)
    t[y + i][x] = f2bf(in[(size_t)(bk + y + i) * N + bn + x]);
  __syncthreads();
#pragma unroll
  for (int i = 0; i < 32; i += 8)
    out[(size_t)(bn + y + i) * K + bk + x] = t[x][y + i];
}

// ---------------- generic GEMM: C[M,N] = act(A[M,K] @ Bt[N,K]^T + bias) ----------------
__global__ __launch_bounds__(256) void gemm_k(
    const u16* __restrict__ A, const u16* __restrict__ Bt,
    const float* __restrict__ bias, u16* __restrict__ Cbf, float* __restrict__ Cf,
    int N, int K, int act) {
  __shared__ __align__(16) u16 As[128 * 32];
  __shared__ __align__(16) u16 Bs[128 * 32];
  int tid = threadIdx.x;
  int lane = tid & 63, w = tid >> 6;
  int wm = w >> 1, wn = w & 1;
  int mm = lane & 15, kh = lane >> 4;
  int m0 = blockIdx.y * 128, n0 = blockIdx.x * 128;

  f32x4 zero = {0.f, 0.f, 0.f, 0.f};
  f32x4 acc[4][4];
#pragma unroll
  for (int i = 0; i < 4; ++i)
#pragma unroll
    for (int j = 0; j < 4; ++j) acc[i][j] = zero;

  for (int kt = 0; kt < K; kt += 32) {
#pragma unroll
    for (int it = 0; it < 2; ++it) {
      int q = tid + it * 256;
      int row = q >> 2, kc = (q & 3) * 8;
      async16(A  + (size_t)(m0 + row) * K + kt + kc, &As[q * 8]);
      async16(Bt + (size_t)(n0 + row) * K + kt + kc, &Bs[q * 8]);
    }
    __syncthreads();
    bf16x8 av[4], bv[4];
#pragma unroll
    for (int i = 0; i < 4; ++i) {
      av[i] = *(const bf16x8*)&As[(wm * 64 + i * 16 + mm) * 32 + kh * 8];
      bv[i] = *(const bf16x8*)&Bs[(wn * 64 + i * 16 + mm) * 32 + kh * 8];
    }
#pragma unroll
    for (int im = 0; im < 4; ++im)
#pragma unroll
      for (int in = 0; in < 4; ++in)
        acc[im][in] = __builtin_amdgcn_mfma_f32_16x16x32_bf16(av[im], bv[in], acc[im][in], 0, 0, 0);
    __syncthreads();
  }

#pragma unroll
  for (int im = 0; im < 4; ++im)
#pragma unroll
    for (int in = 0; in < 4; ++in)
#pragma unroll
      for (int r = 0; r < 4; ++r) {
        int gm = m0 + wm * 64 + im * 16 + kh * 4 + r;
        int gn = n0 + wn * 64 + in * 16 + mm;
        float v = acc[im][in][r] + bias[gn];
        if (act) v = fmaxf(v, 0.f);
        size_t off = (size_t)gm * N + gn;
        if (Cbf) Cbf[off] = f2bf(v);
        if (Cf)  Cf[off]  = v;
      }
}

// ---------------- row L2-normalize [rows,256] bf16 -> bf16 (optional pack t<500) ------
__global__ __launch_bounds__(256) void norm_k(const u16* __restrict__ in,
                                              u16* __restrict__ out, int pack) {
  int row = blockIdx.x * 4 + (threadIdx.x >> 6);
  int lane = threadIdx.x & 63;
  ushort4 v = ((const ushort4*)(in + (size_t)row * 256))[lane];
  float a = bf2f(v.x), b = bf2f(v.y), c = bf2f(v.z), d = bf2f(v.w);
  float s = a * a + b * b + c * c + d * d;
#pragma unroll
  for (int o = 32; o; o >>= 1) s += __shfl_xor(s, o);
  float rn = rsqrtf(s);
  int orow = row;
  if (pack) {
    int bb = row >> 9, tt = row & 511;
    if (tt >= 500) return;
    orow = bb * 500 + tt;
  }
  ushort4 o4;
  o4.x = f2bf(a * rn); o4.y = f2bf(b * rn);
  o4.z = f2bf(c * rn); o4.w = f2bf(d * rn);
  *(ushort4*)(out + (size_t)orow * 256 + lane * 4) = o4;
}

// ---------------- persistent GRU: 16 WGs, exchange at Infinity Cache -----------------
// Hybrid exchange: tag-validated 8B data units (fire & forget, no ack) + packed
// flag trigger (1-line poll). Double-buffered by step parity; a role can only
// overwrite parity t&1 after consuming all roles' t+1 units, which are
// published only after their parity-t&1 reads completed — so
// overwrite-before-read is impossible; flag racing ahead of data is caught by
// the wide-load tag validation loop. Raw LDS-only barriers (bar_lds) keep the
// xi prefetches / output stores in flight across phases. Waves 0-3: h exchange
// + combine; 0-5: MFMA; 6-7: xi prefetch (2-deep) + cf/cbf outputs (1-step
// delayed).
#define HS 520

__global__ __launch_bounds__(512, 1) void gru_k(
    const u16* __restrict__ xi, const float* __restrict__ WH,
    const float* __restrict__ BHN, float* __restrict__ cf,
    u16* __restrict__ cbf, u16* hbuf, u32* flags) {
  __shared__ __align__(16) u16 hs[16 * HS];
  __shared__ float xis[2 * 1536];
  __shared__ float gts[1536];
  __shared__ float hnf[512];

  int tid = threadIdx.x;
  int role = blockIdx.x;                   // 0..15
  int c0 = role * 32;
  char* hb8 = (char*)hbuf;                 // 2 × 32KB unit buffers

  int lane = tid & 63, w = tid >> 6;
  int mm = lane & 15, kh = lane >> 4;

  // persistent B-fragments (waves 0-5): gate cols {r,u,n} x 16, k-major
  bf16x8 wf[16];
  if (w < 6) {
    int gcol = (w >> 1) * 512 + c0 + (w & 1) * 16 + mm;
    int kb = kh * 8;
#pragma unroll
    for (int kk = 0; kk < 16; ++kk) {
      bf16x8 tf;
#pragma unroll
      for (int j = 0; j < 8; ++j)
        tf[j] = (short)f2bf(WH[(size_t)(kk * 32 + kb + j) * 1536 + gcol]);
      wf[kk] = tf;
    }
  }
  // combine constants (waves 0-3: 2 adjacent cols per thread)
  int cr = tid >> 4, cj = (tid & 15) * 2;
  float bhn0 = 0.f, bhn1 = 0.f;
  if (w < 4) { bhn0 = BHN[c0 + cj]; bhn1 = BHN[c0 + cj + 1]; }

  // xi pipeline (waves 6-7): 12 values/thread/step, 2-step prefetch
  int tt = tid - 384;
  size_t xoff[12];
  u16 xpre[12];
  if (w >= 6) {
#pragma unroll
    for (int j = 0; j < 12; ++j) {
      int v = j * 128 + tt;
      int b = v / 96, q = v - b * 96;
      int gcol = (q >> 5) * 512 + c0 + (q & 31);
      xoff[j] = (size_t)b * 512 * 1536 + gcol;
      xis[v] = bf2f(xi[xoff[j]]);                 // xi(t=0) -> slot 0
    }
#pragma unroll
    for (int j = 0; j < 12; ++j) xpre[j] = xi[xoff[j] + 1536];   // issue xi(1)
  }

  for (int t = 0; t < 512; ++t) {
    // ---- phase A ----
    if (w < 4) {                       // h staging: flag trigger + tag validate
      if (t == 0) {
        for (int i = tid; i < 16 * HS; i += 256) hs[i] = 0;
      } else {
        // this thread: batch = tid>>4, role-slice = tid&15 (16 units = 32 cols)
        const char* hb = hb8 + ((size_t)(t & 1)) * 32768 +
                         ((size_t)((tid >> 4) * 256 + (tid & 15) * 16)) * 8;
        u32 tv = (u32)t;
        int iter = 0;
        const u32* fl = &flags[tid & 15];
        while (ld_u32_ic(fl) < tv) { if (++iter > (1 << 20)) break; }
        u32x4 a, b, c, d, e, f, g2, h;
        for (;;) {                     // wide load + full tag validation
          ld_units_ic(hb, a, b, c, d, e, f, g2, h);
          bool ok = (a.y == tv) & (a.w == tv) & (b.y == tv) & (b.w == tv) &
                    (c.y == tv) & (c.w == tv) & (d.y == tv) & (d.w == tv) &
                    (e.y == tv) & (e.w == tv) & (f.y == tv) & (f.w == tv) &
                    (g2.y == tv) & (g2.w == tv) & (h.y == tv) & (h.w == tv);
          if (ok || ++iter > (1 << 20)) break;
        }
        u32x4* dst = (u32x4*)&hs[(tid >> 4) * HS + (tid & 15) * 32];
        u32x4 o0, o1, o2, o3;
        o0.x = a.x;  o0.y = a.z;  o0.z = b.x;  o0.w = b.z;
        o1.x = c.x;  o1.y = c.z;  o1.z = d.x;  o1.w = d.z;
        o2.x = e.x;  o2.y = e.z;  o2.z = f.x;  o2.w = f.z;
        o3.x = g2.x; o3.y = g2.z; o3.z = h.x;  o3.w = h.z;
        dst[0] = o0; dst[1] = o1; dst[2] = o2; dst[3] = o3;
      }
    } else if (w >= 6) {               // outputs(t-1) + xi pipeline (own vmcnt)
      if (t > 0) {
        int v = tt * 4;
        int b = v >> 5, col = v & 31;
        size_t co = ((size_t)b * 512 + (t - 1)) * 512 + c0 + col;
        float4 o;
        o.x = hnf[v]; o.y = hnf[v + 1]; o.z = hnf[v + 2]; o.w = hnf[v + 3];
        *(float4*)&cf[co] = o;
        uint2 pk;
        pk.x = (u32)f2bf(o.x) | ((u32)f2bf(o.y) << 16);
        pk.y = (u32)f2bf(o.z) | ((u32)f2bf(o.w) << 16);
        *(uint2*)&cbf[co] = pk;
      }
      if (t < 511) {
        float* xd = &xis[((t + 1) & 1) * 1536];
#pragma unroll
        for (int j = 0; j < 12; ++j) xd[j * 128 + tt] = bf2f(xpre[j]);
      }
      if (t < 510) {
        const u16* xs = xi + (size_t)(t + 2) * 1536;
#pragma unroll
        for (int j = 0; j < 12; ++j) xpre[j] = xs[xoff[j]];
      }
    }
    bar_lds();

    // ---- phase B: hp = h @ WH[:, my 16 gate cols] ----
    if (w < 6) {
      f32x4 acc = {0.f, 0.f, 0.f, 0.f};
#pragma unroll
      for (int kk = 0; kk < 16; ++kk) {
        bf16x8 a = *(const bf16x8*)&hs[mm * HS + kk * 32 + kh * 8];
        acc = __builtin_amdgcn_mfma_f32_16x16x32_bf16(a, wf[kk], acc, 0, 0, 0);
      }
      int gc = (w >> 1) * 32 + (w & 1) * 16 + mm;
#pragma unroll
      for (int r = 0; r < 4; ++r) gts[(kh * 4 + r) * 96 + gc] = acc[r];
    }
    bar_lds();

    // ---- phase C: combine (waves 0-3, 2 cols/thread); publish units (fire&forget) --
    if (w < 4) {
      const float* xc = &xis[(t & 1) * 1536] + cr * 96;
      const float* gr_ = &gts[cr * 96];
      float hp0 = bf2f(hs[cr * HS + c0 + cj]);
      float hp1 = bf2f(hs[cr * HS + c0 + cj + 1]);
      float r0 = 1.f / (1.f + __expf(-(xc[cj] + gr_[cj])));
      float u0 = 1.f / (1.f + __expf(-(xc[32 + cj] + gr_[32 + cj])));
      float nx0 = xc[64 + cj] + r0 * (gr_[64 + cj] + bhn0);
      float n0 = 1.f - 2.f / (__expf(2.f * nx0) + 1.f);
      float h0 = (1.f - u0) * n0 + u0 * hp0;
      float r1 = 1.f / (1.f + __expf(-(xc[cj + 1] + gr_[cj + 1])));
      float u1 = 1.f / (1.f + __expf(-(xc[33 + cj] + gr_[33 + cj])));
      float nx1 = xc[65 + cj] + r1 * (gr_[65 + cj] + bhn1);
      float n1 = 1.f - 2.f / (__expf(2.f * nx1) + 1.f);
      float h1v = (1.f - u1) * n1 + u1 * hp1;
      hnf[cr * 32 + cj] = h0;
      hnf[cr * 32 + cj + 1] = h1v;
      u32x2 un;
      un.x = (u32)f2bf(h0) | ((u32)f2bf(h1v) << 16);
      un.y = (u32)(t + 1);
      st_unit_ic(hb8 + ((size_t)((t + 1) & 1)) * 32768 +
                 ((size_t)(cr * 256 + role * 16 + (tid & 15))) * 8, un);
    }
    bar_lds();
    // trigger flag: all 256 unit stores ISSUED (barrier above); no ack needed —
    // readers validate tags and re-load on the rare straggler.
    if (tid == 0) st_u32_ic(&flags[role], (u32)(t + 1));
  }

  // epilogue: outputs for t=511
  if (w >= 6) {
    int v = tt * 4;
    int b = v >> 5, col = v & 31;
    size_t co = ((size_t)b * 512 + 511) * 512 + c0 + col;
    float4 o;
    o.x = hnf[v]; o.y = hnf[v + 1]; o.z = hnf[v + 2]; o.w = hnf[v + 3];
    *(float4*)&cf[co] = o;
    uint2 pk;
    pk.x = (u32)f2bf(o.x) | ((u32)f2bf(o.y) << 16);
    pk.y = (u32)f2bf(o.z) | ((u32)f2bf(o.w) << 16);
    *(uint2*)&cbf[co] = pk;
  }
}

// ---------------- S = p . zhat^T fused with exp/g-reduction + diag capture -----------
__global__ __launch_bounds__(256) void sgemm_k(
    const u16* __restrict__ P, const u16* __restrict__ Z,
    float* __restrict__ g, float* __restrict__ diag) {
  __shared__ __align__(16) u16 Ap[128 * 256];
  __shared__ __align__(16) u16 Bs[128 * 32];
  __shared__ float gacc[128 * 128];
  int tid = threadIdx.x;
  int lane = tid & 63, w = tid >> 6;
  int wm = w >> 1, wn = w & 1;
  int mm = lane & 15, kh = lane >> 4;
  int r0 = blockIdx.y * 128, t0 = blockIdx.x * 128;

#pragma unroll
  for (int it = 0; it < 16; ++it) {
    int q = tid + it * 256;
    int row = q >> 5, kc = (q & 31) * 8;
    async16(P + (size_t)(r0 + row) * 256 + kc, &Ap[q * 8]);
  }
  for (int i = tid; i < 128 * 128; i += 256) gacc[i] = 0.f;
  __syncthreads();

  f32x4 zero = {0.f, 0.f, 0.f, 0.f};
  for (int b = 0; b < 16; ++b) {
    int n0 = b * 512 + t0;
    f32x4 acc[4][4];
#pragma unroll
    for (int i = 0; i < 4; ++i)
#pragma unroll
      for (int j = 0; j < 4; ++j) acc[i][j] = zero;

    for (int kk = 0; kk < 8; ++kk) {
#pragma unroll
      for (int it = 0; it < 2; ++it) {
        int q = tid + it * 256;
        int row = q >> 2, kc = (q & 3) * 8;
        async16(Z + (size_t)(n0 + row) * 256 + kk * 32 + kc, &Bs[q * 8]);
      }
      __syncthreads();
      bf16x8 av[4], bv[4];
#pragma unroll
      for (int i = 0; i < 4; ++i) {
        av[i] = *(const bf16x8*)&Ap[(wm * 64 + i * 16 + mm) * 256 + kk * 32 + kh * 8];
        bv[i] = *(const bf16x8*)&Bs[(wn * 64 + i * 16 + mm) * 32 + kh * 8];
      }
#pragma unroll
      for (int im = 0; im < 4; ++im)
#pragma unroll
        for (int in = 0; in < 4; ++in)
          acc[im][in] = __builtin_amdgcn_mfma_f32_16x16x32_bf16(av[im], bv[in], acc[im][in], 0, 0, 0);
      __syncthreads();
    }
#pragma unroll
    for (int im = 0; im < 4; ++im)
#pragma unroll
      for (int in = 0; in < 4; ++in)
#pragma unroll
        for (int r = 0; r < 4; ++r) {
          int row = wm * 64 + im * 16 + kh * 4 + r;
          int col = wn * 64 + in * 16 + mm;
          float s10 = acc[im][in][r] * 10.f;
          gacc[row * 128 + col] += __expf(s10 - 10.f);
          int ig = r0 + row;
          if (ig < 8000) {
            int bi = ig / 500;
            if (bi == b) {
              int ti = ig - bi * 500;
              int dt = t0 + col - ti;
              if (dt >= 1 && dt <= 12) diag[(size_t)ig * 12 + dt - 1] = s10;
            }
          }
        }
  }
  __syncthreads();
  for (int i = tid; i < 128 * 128; i += 256) {
    int row = i >> 7, col = i & 127;
    g[(size_t)(r0 + row) * 512 + t0 + col] = gacc[i];
  }
}

// ---------------- window logsumexp + loss partial sums (one wave per row) ------------
__global__ __launch_bounds__(256) void win_k(const float* __restrict__ g,
                                             const float* __restrict__ diag,
                                             float* __restrict__ acc) {
  __shared__ float lo[4][16], hi[4][16];
  int w = threadIdx.x >> 6, lane = threadIdx.x & 63;
  int row = blockIdx.x * 4 + w;
  const float* gr = g + (size_t)row * 512;
  float4 a = ((const float4*)gr)[lane * 2];
  float4 b = ((const float4*)gr)[lane * 2 + 1];
  float s = a.x + a.y + a.z + a.w + b.x + b.y + b.z + b.w;
#pragma unroll
  for (int o = 32; o; o >>= 1) s += __shfl_xor(s, o);
  if (lane == 0) { lo[w][0]=a.x; lo[w][1]=a.y; lo[w][2]=a.z; lo[w][3]=a.w;
                   lo[w][4]=b.x; lo[w][5]=b.y; lo[w][6]=b.z; lo[w][7]=b.w; }
  if (lane == 1) { lo[w][8]=a.x; lo[w][9]=a.y; lo[w][10]=a.z; lo[w][11]=a.w; }
  if (lane == 62){ hi[w][0]=b.x; hi[w][1]=b.y; hi[w][2]=b.z; hi[w][3]=b.w; }
  if (lane == 63){ hi[w][4]=a.x; hi[w][5]=a.y; hi[w][6]=a.z; hi[w][7]=a.w;
                   hi[w][8]=b.x; hi[w][9]=b.y; hi[w][10]=b.z; hi[w][11]=b.w; }
  __syncthreads();
  float term = 0.f;
  if (lane < 12) {
    int k = lane + 1;
    float pre = 0.f, suf = 0.f;
#pragma unroll
    for (int j = 0; j < 12; ++j) {
      if (j < k) pre += lo[w][j];
      if (j >= k) suf += hi[w][j];
    }
    float W = s - pre - suf;
    term = diag[(size_t)row * 12 + lane] - __logf(W) - 10.f;
  }
#pragma unroll
  for (int o = 32; o; o >>= 1) term += __shfl_xor(term, o);
  if (lane == 0) atomicAdd(acc, term);
}

__global__ void fin_k(const float* acc, float* lout) {
  lout[0] = -acc[0] * (1.f / 96000.f);
}

// ============================== launch ==============================
extern "C" void kernel_launch(void* const* d_in, const int* in_sizes, int n_in,
                              void* d_out, int out_size, void* d_ws, size_t ws_size,
                              hipStream_t stream) {
  (void)in_sizes; (void)n_in; (void)out_size; (void)ws_size;
  const float* x    = (const float*)d_in[0];
  const float* ew1  = (const float*)d_in[1];
  const float* eb1  = (const float*)d_in[2];
  const float* ew2  = (const float*)d_in[3];
  const float* eb2  = (const float*)d_in[4];
  const float* ew3  = (const float*)d_in[5];
  const float* eb3  = (const float*)d_in[6];
  const float* gwi  = (const float*)d_in[7];
  const float* gbi  = (const float*)d_in[8];
  const float* gwh  = (const float*)d_in[9];
  const float* gbhn = (const float*)d_in[10];
  const float* pw1  = (const float*)d_in[11];
  const float* pb1  = (const float*)d_in[12];
  const float* pw2  = (const float*)d_in[13];
  const float* pb2  = (const float*)d_in[14];

  char* W = (char*)d_ws;
  u32*   flags = (u32*)(W + 64);        // [16] per-role step flags (one line)
  float* lacc = (float*)(W + 2048);
  u16*   w1T  = (u16*)(W + 4096);
  u16*   w2T  = (u16*)(W + 135168);
  u16*   w3T  = (u16*)(W + 659456);
  u16*   wiT  = (u16*)(W + 921600);
  u16*   p1T  = (u16*)(W + 1708032);
  u16*   p2T  = (u16*)(W + 2232320);
  u16*   hbuf = (u16*)(W + 2494464);    // 2 × 32KB self-validating unit buffers
  float* diag = (float*)(W + 2560000);
  u16*   zhat = (u16*)(W + 2944000);
  u16*   zbf  = (u16*)(W + 7138304);    // g3 out, dead after g4
  u16*   cbf  = (u16*)(W + 7138304);    // gru out (after zbf dead)
  u16*   ppk  = (u16*)(W + 7138304);    // norm2 out (after cbf dead)
  u16*   xi   = (u16*)(W + 15526912);
  u16*   xbf  = (u16*)(W + 15526912);   // alias (dead before xi written)
  u16*   h1   = (u16*)(W + 17624064);   // alias
  u16*   h2   = (u16*)(W + 26012672);   // alias
  float* g    = (float*)(W + 15526912); // alias (xi dead after gru)

  float* zf    = (float*)d_out;
  float* cf    = zf + 2097152;
  float* lout  = zf + 6291456;

  hipMemsetAsync(d_ws, 0, 4096, stream);         // zero flags + lacc
  hipMemsetAsync((void*)hbuf, 0, 65536, stream); // zero exchange units (stale tag guard)

  cvt_k<<<1024, 256, 0, stream>>>((const float4*)x, (ushort4*)xbf);

  dim3 tb(32, 8);
  tr_k<<<dim3(16, 4),  tb, 0, stream>>>(ew1, w1T, 128, 512);
  tr_k<<<dim3(16, 16), tb, 0, stream>>>(ew2, w2T, 512, 512);
  tr_k<<<dim3(8, 16),  tb, 0, stream>>>(ew3, w3T, 512, 256);
  tr_k<<<dim3(48, 8),  tb, 0, stream>>>(gwi, wiT, 256, 1536);
  tr_k<<<dim3(16, 16), tb, 0, stream>>>(pw1, p1T, 512, 512);
  tr_k<<<dim3(8, 16),  tb, 0, stream>>>(pw2, p2T, 512, 256);

  gemm_k<<<dim3(4, 64),  256, 0, stream>>>(xbf,  w1T, eb1, h1,  nullptr, 512, 128, 1);
  gemm_k<<<dim3(4, 64),  256, 0, stream>>>(h1,   w2T, eb2, h2,  nullptr, 512, 512, 1);
  gemm_k<<<dim3(2, 64),  256, 0, stream>>>(h2,   w3T, eb3, zbf, zf,      256, 512, 0);
  norm_k<<<2048, 256, 0, stream>>>(zbf, zhat, 0);
  gemm_k<<<dim3(12, 64), 256, 0, stream>>>(zbf,  wiT, gbi, xi,  nullptr, 1536, 256, 0);
  gru_k<<<16, 512, 0, stream>>>(xi, gwh, gbhn, cf, cbf, hbuf, flags);
  gemm_k<<<dim3(4, 64),  256, 0, stream>>>(cbf,  p1T, pb1, h1,  nullptr, 512, 512, 1);
  gemm_k<<<dim3(2, 64),  256, 0, stream>>>(h1,   p2T, pb2, h2,  nullptr, 256, 512, 0);
  norm_k<<<2048, 256, 0, stream>>>(h2, ppk, 1);
  sgemm_k<<<dim3(4, 63), 256, 0, stream>>>(ppk, zhat, g, diag);
  win_k<<<2000, 256, 0, stream>>>(g, diag, lacc);
  fin_k<<<1, 1, 0, stream>>>(lacc, lout);
}

// Round 5
// 1912.690 us; speedup vs baseline: 1.1701x; 1.1701x over previous
//
#include <hip/hip_runtime.h>
#include <cstdint>
#include <cstddef>

typedef unsigned short u16;
typedef unsigned int   u32;
typedef unsigned long long u64;
typedef __attribute__((ext_vector_type(8))) short bf16x8;   // 8 bf16 = 4 VGPRs
typedef __attribute__((ext_vector_type(4))) float f32x4;
typedef __attribute__((ext_vector_type(4))) unsigned int u32x4;

typedef __attribute__((address_space(1))) const unsigned int as1c_uint;
typedef __attribute__((address_space(3))) unsigned int as3_uint;

__device__ __forceinline__ void async16(const void* g, void* l) {
  __builtin_amdgcn_global_load_lds((as1c_uint*)g, (as3_uint*)l, 16, 0, 0);
}
__device__ __forceinline__ float bf2f(u16 u) {
  return __uint_as_float(((u32)u) << 16);
}
__device__ __forceinline__ u16 f2bf(float x) {
  u32 u = __float_as_uint(x);
  u32 r = u + 0x7FFFu + ((u >> 16) & 1u);
  return (u16)(r >> 16);
}

// LDS-only barrier: orders LDS ops (lgkmcnt(0) before s_barrier) WITHOUT
// draining vmcnt — in-flight global prefetch loads / output stores survive.
// (__syncthreads compiles to s_waitcnt vmcnt(0) lgkmcnt(0); s_barrier, which
// put waves 6-7's 12 HBM prefetch loads + output-store acks on every wave's
// critical path each step.)
__device__ __forceinline__ void bar_lds() {
  asm volatile("s_waitcnt lgkmcnt(0)" ::: "memory");
  __builtin_amdgcn_s_barrier();
  asm volatile("" ::: "memory");
}

// ---- IC-scope ops (sc0 sc1: bypass L1+L2, serviced at Infinity Cache — the
// cross-XCD coherence point). Round-0 protocol: publisher h-store(IC) ->
// vmcnt(0) ack -> barrier -> flag-store(IC); readers poll one packed flag line
// then wide-load the h slice. Flag is post-ack, so readers never re-spin. ----
__device__ __forceinline__ u32 ld_u32_ic(const void* p) {
  u32 v;
  asm volatile("global_load_dword %0, %1, off sc0 sc1\n\ts_waitcnt vmcnt(0)"
               : "=v"(v) : "v"(p) : "memory");
  return v;
}
__device__ __forceinline__ void st_u32_ic(void* p, u32 v) {
  asm volatile("global_store_dword %0, %1, off sc0 sc1" :: "v"(p), "v"(v) : "memory");
}
__device__ __forceinline__ void ld_h64_ic(const void* p, u32x4& a, u32x4& b,
                                          u32x4& c, u32x4& d) {
  asm volatile(
      "global_load_dwordx4 %0, %4, off sc0 sc1\n\t"
      "global_load_dwordx4 %1, %4, off offset:16 sc0 sc1\n\t"
      "global_load_dwordx4 %2, %4, off offset:32 sc0 sc1\n\t"
      "global_load_dwordx4 %3, %4, off offset:48 sc0 sc1\n\t"
      "s_waitcnt vmcnt(0)"
      : "=&v"(a), "=&v"(b), "=&v"(c), "=&v"(d) : "v"(p) : "memory");
}

// ---------------- fp32 -> bf16 convert (x) ----------------
__global__ void cvt_k(const float4* __restrict__ in, ushort4* __restrict__ out) {
  int i = blockIdx.x * 256 + threadIdx.x;
  float4 v = in[i];
  ushort4 o;
  o.x = f2bf(v.x); o.y = f2bf(v.y); o.z = f2bf(v.z); o.w = f2bf(v.w);
  out[i] = o;
}

// ---------------- transpose+convert: out[n*K+k] = bf16(in[k*N+n]) ----------------
__global__ void tr_k(const float* __restrict__ in, u16* __restrict__ out, int K, int N) {
  __shared__ u16 t[32][33];
  int bn = blockIdx.x * 32, bk = blockIdx.y * 32;
  int x = threadIdx.x, y = threadIdx.y;
#pragma unroll
  for (int i = 0; i < 32; i += 8)
    t[y + i][x] = f2bf(in[(size_t)(bk + y + i) * N + bn + x]);
  __syncthreads();
#pragma unroll
  for (int i = 0; i < 32; i += 8)
    out[(size_t)(bn + y + i) * K + bk + x] = t[x][y + i];
}

// ---------------- generic GEMM: C[M,N] = act(A[M,K] @ Bt[N,K]^T + bias) ----------------
__global__ __launch_bounds__(256) void gemm_k(
    const u16* __restrict__ A, const u16* __restrict__ Bt,
    const float* __restrict__ bias, u16* __restrict__ Cbf, float* __restrict__ Cf,
    int N, int K, int act) {
  __shared__ __align__(16) u16 As[128 * 32];
  __shared__ __align__(16) u16 Bs[128 * 32];
  int tid = threadIdx.x;
  int lane = tid & 63, w = tid >> 6;
  int wm = w >> 1, wn = w & 1;
  int mm = lane & 15, kh = lane >> 4;
  int m0 = blockIdx.y * 128, n0 = blockIdx.x * 128;

  f32x4 zero = {0.f, 0.f, 0.f, 0.f};
  f32x4 acc[4][4];
#pragma unroll
  for (int i = 0; i < 4; ++i)
#pragma unroll
    for (int j = 0; j < 4; ++j) acc[i][j] = zero;

  for (int kt = 0; kt < K; kt += 32) {
#pragma unroll
    for (int it = 0; it < 2; ++it) {
      int q = tid + it * 256;
      int row = q >> 2, kc = (q & 3) * 8;
      async16(A  + (size_t)(m0 + row) * K + kt + kc, &As[q * 8]);
      async16(Bt + (size_t)(n0 + row) * K + kt + kc, &Bs[q * 8]);
    }
    __syncthreads();
    bf16x8 av[4], bv[4];
#pragma unroll
    for (int i = 0; i < 4; ++i) {
      av[i] = *(const bf16x8*)&As[(wm * 64 + i * 16 + mm) * 32 + kh * 8];
      bv[i] = *(const bf16x8*)&Bs[(wn * 64 + i * 16 + mm) * 32 + kh * 8];
    }
#pragma unroll
    for (int im = 0; im < 4; ++im)
#pragma unroll
      for (int in = 0; in < 4; ++in)
        acc[im][in] = __builtin_amdgcn_mfma_f32_16x16x32_bf16(av[im], bv[in], acc[im][in], 0, 0, 0);
    __syncthreads();
  }

#pragma unroll
  for (int im = 0; im < 4; ++im)
#pragma unroll
    for (int in = 0; in < 4; ++in)
#pragma unroll
      for (int r = 0; r < 4; ++r) {
        int gm = m0 + wm * 64 + im * 16 + kh * 4 + r;
        int gn = n0 + wn * 64 + in * 16 + mm;
        float v = acc[im][in][r] + bias[gn];
        if (act) v = fmaxf(v, 0.f);
        size_t off = (size_t)gm * N + gn;
        if (Cbf) Cbf[off] = f2bf(v);
        if (Cf)  Cf[off]  = v;
      }
}

// ---------------- row L2-normalize [rows,256] bf16 -> bf16 (optional pack t<500) ------
__global__ __launch_bounds__(256) void norm_k(const u16* __restrict__ in,
                                              u16* __restrict__ out, int pack) {
  int row = blockIdx.x * 4 + (threadIdx.x >> 6);
  int lane = threadIdx.x & 63;
  ushort4 v = ((const ushort4*)(in + (size_t)row * 256))[lane];
  float a = bf2f(v.x), b = bf2f(v.y), c = bf2f(v.z), d = bf2f(v.w);
  float s = a * a + b * b + c * c + d * d;
#pragma unroll
  for (int o = 32; o; o >>= 1) s += __shfl_xor(s, o);
  float rn = rsqrtf(s);
  int orow = row;
  if (pack) {
    int bb = row >> 9, tt = row & 511;
    if (tt >= 500) return;
    orow = bb * 500 + tt;
  }
  ushort4 o4;
  o4.x = f2bf(a * rn); o4.y = f2bf(b * rn);
  o4.z = f2bf(c * rn); o4.w = f2bf(d * rn);
  *(ushort4*)(out + (size_t)orow * 256 + lane * 4) = o4;
}

// ---------------- persistent GRU: 16 WGs, exchange at Infinity Cache -----------------
// Round-0 flag protocol (publisher h-store(IC) -> vmcnt(0) -> flag-store;
// readers poll one flag then wide-load the h slice) with LDS-only barriers:
// the ONLY change vs the 1475µs baseline is bar_lds() replacing __syncthreads,
// keeping waves 6-7's xi prefetches / output stores in flight across phases.
// Waves 0-3: h exchange + combine; 0-5: MFMA; 6-7: xi prefetch (2-deep) +
// cf/cbf outputs (1-step delayed).
#define HS 520

__global__ __launch_bounds__(512, 1) void gru_k(
    const u16* __restrict__ xi, const float* __restrict__ WH,
    const float* __restrict__ BHN, float* __restrict__ cf,
    u16* __restrict__ cbf, u16* hbuf, u32* flags) {
  __shared__ __align__(16) u16 hs[16 * HS];
  __shared__ float xis[2 * 1536];
  __shared__ float gts[1536];
  __shared__ float hnf[512];

  int tid = threadIdx.x;
  int role = blockIdx.x;                   // 0..15
  int c0 = role * 32;

  int lane = tid & 63, w = tid >> 6;
  int mm = lane & 15, kh = lane >> 4;

  // persistent B-fragments (waves 0-5): gate cols {r,u,n} x 16, k-major
  bf16x8 wf[16];
  if (w < 6) {
    int gcol = (w >> 1) * 512 + c0 + (w & 1) * 16 + mm;
    int kb = kh * 8;
#pragma unroll
    for (int kk = 0; kk < 16; ++kk) {
      bf16x8 tf;
#pragma unroll
      for (int j = 0; j < 8; ++j)
        tf[j] = (short)f2bf(WH[(size_t)(kk * 32 + kb + j) * 1536 + gcol]);
      wf[kk] = tf;
    }
  }
  // combine constants (waves 0-3: 2 adjacent cols per thread)
  int cr = tid >> 4, cj = (tid & 15) * 2;
  float bhn0 = 0.f, bhn1 = 0.f;
  if (w < 4) { bhn0 = BHN[c0 + cj]; bhn1 = BHN[c0 + cj + 1]; }

  // xi pipeline (waves 6-7): 12 values/thread/step, 2-step prefetch
  int tt = tid - 384;
  size_t xoff[12];
  u16 xpre[12];
  if (w >= 6) {
#pragma unroll
    for (int j = 0; j < 12; ++j) {
      int v = j * 128 + tt;
      int b = v / 96, q = v - b * 96;
      int gcol = (q >> 5) * 512 + c0 + (q & 31);
      xoff[j] = (size_t)b * 512 * 1536 + gcol;
      xis[v] = bf2f(xi[xoff[j]]);                 // xi(t=0) -> slot 0
    }
#pragma unroll
    for (int j = 0; j < 12; ++j) xpre[j] = xi[xoff[j] + 1536];   // issue xi(1)
  }

  for (int t = 0; t < 512; ++t) {
    // ---- phase A ----
    if (w < 4) {                       // h staging via IC (clean vmcnt path)
      if (t == 0) {
        for (int i = tid; i < 16 * HS; i += 256) hs[i] = 0;
      } else {
        int iter = 0;
        const u32* fl = &flags[tid & 15];
        while (ld_u32_ic(fl) < (u32)t) { if (++iter > (1 << 20)) break; }
        const u16* hb = hbuf + (size_t)(t & 1) * 8192 + (tid >> 4) * 512 + (tid & 15) * 32;
        u32x4 a, b, c, d;
        ld_h64_ic(hb, a, b, c, d);
        u32x4* dst = (u32x4*)&hs[(tid >> 4) * HS + (tid & 15) * 32];
        dst[0] = a; dst[1] = b; dst[2] = c; dst[3] = d;
      }
    } else if (w >= 6) {               // outputs(t-1) + xi pipeline (own vmcnt)
      if (t > 0) {
        int v = tt * 4;
        int b = v >> 5, col = v & 31;
        size_t co = ((size_t)b * 512 + (t - 1)) * 512 + c0 + col;
        float4 o;
        o.x = hnf[v]; o.y = hnf[v + 1]; o.z = hnf[v + 2]; o.w = hnf[v + 3];
        *(float4*)&cf[co] = o;
        uint2 pk;
        pk.x = (u32)f2bf(o.x) | ((u32)f2bf(o.y) << 16);
        pk.y = (u32)f2bf(o.z) | ((u32)f2bf(o.w) << 16);
        *(uint2*)&cbf[co] = pk;
      }
      if (t < 511) {
        float* xd = &xis[((t + 1) & 1) * 1536];
#pragma unroll
        for (int j = 0; j < 12; ++j) xd[j * 128 + tt] = bf2f(xpre[j]);
      }
      if (t < 510) {
        const u16* xs = xi + (size_t)(t + 2) * 1536;
#pragma unroll
        for (int j = 0; j < 12; ++j) xpre[j] = xs[xoff[j]];
      }
    }
    bar_lds();

    // ---- phase B: hp = h @ WH[:, my 16 gate cols] ----
    if (w < 6) {
      f32x4 acc = {0.f, 0.f, 0.f, 0.f};
#pragma unroll
      for (int kk = 0; kk < 16; ++kk) {
        bf16x8 a = *(const bf16x8*)&hs[mm * HS + kk * 32 + kh * 8];
        acc = __builtin_amdgcn_mfma_f32_16x16x32_bf16(a, wf[kk], acc, 0, 0, 0);
      }
      int gc = (w >> 1) * 32 + (w & 1) * 16 + mm;
#pragma unroll
      for (int r = 0; r < 4; ++r) gts[(kh * 4 + r) * 96 + gc] = acc[r];
    }
    bar_lds();

    // ---- phase C: combine (waves 0-3, 2 cols/thread); publish h(IC); ack; flag ----
    if (w < 4) {
      const float* xc = &xis[(t & 1) * 1536] + cr * 96;
      const float* gr_ = &gts[cr * 96];
      float hp0 = bf2f(hs[cr * HS + c0 + cj]);
      float hp1 = bf2f(hs[cr * HS + c0 + cj + 1]);
      float r0 = 1.f / (1.f + __expf(-(xc[cj] + gr_[cj])));
      float u0 = 1.f / (1.f + __expf(-(xc[32 + cj] + gr_[32 + cj])));
      float nx0 = xc[64 + cj] + r0 * (gr_[64 + cj] + bhn0);
      float n0 = 1.f - 2.f / (__expf(2.f * nx0) + 1.f);
      float h0 = (1.f - u0) * n0 + u0 * hp0;
      float r1 = 1.f / (1.f + __expf(-(xc[cj + 1] + gr_[cj + 1])));
      float u1 = 1.f / (1.f + __expf(-(xc[33 + cj] + gr_[33 + cj])));
      float nx1 = xc[65 + cj] + r1 * (gr_[65 + cj] + bhn1);
      float n1 = 1.f - 2.f / (__expf(2.f * nx1) + 1.f);
      float h1v = (1.f - u1) * n1 + u1 * hp1;
      hnf[cr * 32 + cj] = h0;
      hnf[cr * 32 + cj + 1] = h1v;
      u32 pk = (u32)f2bf(h0) | ((u32)f2bf(h1v) << 16);
      st_u32_ic(hbuf + (size_t)((t + 1) & 1) * 8192 + cr * 512 + c0 + cj, pk);
      asm volatile("s_waitcnt vmcnt(0)" ::: "memory");   // h at IC before flag
    }
    bar_lds();
    if (tid == 0) st_u32_ic(&flags[role], (u32)(t + 1));
  }

  // epilogue: outputs for t=511
  if (w >= 6) {
    int v = tt * 4;
    int b = v >> 5, col = v & 31;
    size_t co = ((size_t)b * 512 + 511) * 512 + c0 + col;
    float4 o;
    o.x = hnf[v]; o.y = hnf[v + 1]; o.z = hnf[v + 2]; o.w = hnf[v + 3];
    *(float4*)&cf[co] = o;
    uint2 pk;
    pk.x = (u32)f2bf(o.x) | ((u32)f2bf(o.y) << 16);
    pk.y = (u32)f2bf(o.z) | ((u32)f2bf(o.w) << 16);
    *(uint2*)&cbf[co] = pk;
  }
}

// ---------------- S = p . zhat^T fused with exp/g-reduction + diag capture -----------
__global__ __launch_bounds__(256) void sgemm_k(
    const u16* __restrict__ P, const u16* __restrict__ Z,
    float* __restrict__ g, float* __restrict__ diag) {
  __shared__ __align__(16) u16 Ap[128 * 256];
  __shared__ __align__(16) u16 Bs[128 * 32];
  __shared__ float gacc[128 * 128];
  int tid = threadIdx.x;
  int lane = tid & 63, w = tid >> 6;
  int wm = w >> 1, wn = w & 1;
  int mm = lane & 15, kh = lane >> 4;
  int r0 = blockIdx.y * 128, t0 = blockIdx.x * 128;

#pragma unroll
  for (int it = 0; it < 16; ++it) {
    int q = tid + it * 256;
    int row = q >> 5, kc = (q & 31) * 8;
    async16(P + (size_t)(r0 + row) * 256 + kc, &Ap[q * 8]);
  }
  for (int i = tid; i < 128 * 128; i += 256) gacc[i] = 0.f;
  __syncthreads();

  f32x4 zero = {0.f, 0.f, 0.f, 0.f};
  for (int b = 0; b < 16; ++b) {
    int n0 = b * 512 + t0;
    f32x4 acc[4][4];
#pragma unroll
    for (int i = 0; i < 4; ++i)
#pragma unroll
      for (int j = 0; j < 4; ++j) acc[i][j] = zero;

    for (int kk = 0; kk < 8; ++kk) {
#pragma unroll
      for (int it = 0; it < 2; ++it) {
        int q = tid + it * 256;
        int row = q >> 2, kc = (q & 3) * 8;
        async16(Z + (size_t)(n0 + row) * 256 + kk * 32 + kc, &Bs[q * 8]);
      }
      __syncthreads();
      bf16x8 av[4], bv[4];
#pragma unroll
      for (int i = 0; i < 4; ++i) {
        av[i] = *(const bf16x8*)&Ap[(wm * 64 + i * 16 + mm) * 256 + kk * 32 + kh * 8];
        bv[i] = *(const bf16x8*)&Bs[(wn * 64 + i * 16 + mm) * 32 + kh * 8];
      }
#pragma unroll
      for (int im = 0; im < 4; ++im)
#pragma unroll
        for (int in = 0; in < 4; ++in)
          acc[im][in] = __builtin_amdgcn_mfma_f32_16x16x32_bf16(av[im], bv[in], acc[im][in], 0, 0, 0);
      __syncthreads();
    }
#pragma unroll
    for (int im = 0; im < 4; ++im)
#pragma unroll
      for (int in = 0; in < 4; ++in)
#pragma unroll
        for (int r = 0; r < 4; ++r) {
          int row = wm * 64 + im * 16 + kh * 4 + r;
          int col = wn * 64 + in * 16 + mm;
          float s10 = acc[im][in][r] * 10.f;
          gacc[row * 128 + col] += __expf(s10 - 10.f);
          int ig = r0 + row;
          if (ig < 8000) {
            int bi = ig / 500;
            if (bi == b) {
              int ti = ig - bi * 500;
              int dt = t0 + col - ti;
              if (dt >= 1 && dt <= 12) diag[(size_t)ig * 12 + dt - 1] = s10;
            }
          }
        }
  }
  __syncthreads();
  for (int i = tid; i < 128 * 128; i += 256) {
    int row = i >> 7, col = i & 127;
    g[(size_t)(r0 + row) * 512 + t0 + col] = gacc[i];
  }
}

// ---------------- window logsumexp + loss partial sums (one wave per row) ------------
__global__ __launch_bounds__(256) void win_k(const float* __restrict__ g,
                                             const float* __restrict__ diag,
                                             float* __restrict__ acc) {
  __shared__ float lo[4][16], hi[4][16];
  int w = threadIdx.x >> 6, lane = threadIdx.x & 63;
  int row = blockIdx.x * 4 + w;
  const float* gr = g + (size_t)row * 512;
  float4 a = ((const float4*)gr)[lane * 2];
  float4 b = ((const float4*)gr)[lane * 2 + 1];
  float s = a.x + a.y + a.z + a.w + b.x + b.y + b.z + b.w;
#pragma unroll
  for (int o = 32; o; o >>= 1) s += __shfl_xor(s, o);
  if (lane == 0) { lo[w][0]=a.x; lo[w][1]=a.y; lo[w][2]=a.z; lo[w][3]=a.w;
                   lo[w][4]=b.x; lo[w][5]=b.y; lo[w][6]=b.z; lo[w][7]=b.w; }
  if (lane == 1) { lo[w][8]=a.x; lo[w][9]=a.y; lo[w][10]=a.z; lo[w][11]=a.w; }
  if (lane == 62){ hi[w][0]=b.x; hi[w][1]=b.y; hi[w][2]=b.z; hi[w][3]=b.w; }
  if (lane == 63){ hi[w][4]=a.x; hi[w][5]=a.y; hi[w][6]=a.z; hi[w][7]=a.w;
                   hi[w][8]=b.x; hi[w][9]=b.y; hi[w][10]=b.z; hi[w][11]=b.w; }
  __syncthreads();
  float term = 0.f;
  if (lane < 12) {
    int k = lane + 1;
    float pre = 0.f, suf = 0.f;
#pragma unroll
    for (int j = 0; j < 12; ++j) {
      if (j < k) pre += lo[w][j];
      if (j >= k) suf += hi[w][j];
    }
    float W = s - pre - suf;
    term = diag[(size_t)row * 12 + lane] - __logf(W) - 10.f;
  }
#pragma unroll
  for (int o = 32; o; o >>= 1) term += __shfl_xor(term, o);
  if (lane == 0) atomicAdd(acc, term);
}

__global__ void fin_k(const float* acc, float* lout) {
  lout[0] = -acc[0] * (1.f / 96000.f);
}

// ============================== launch ==============================
extern "C" void kernel_launch(void* const* d_in, const int* in_sizes, int n_in,
                              void* d_out, int out_size, void* d_ws, size_t ws_size,
                              hipStream_t stream) {
  (void)in_sizes; (void)n_in; (void)out_size; (void)ws_size;
  const float* x    = (const float*)d_in[0];
  const float* ew1  = (const float*)d_in[1];
  const float* eb1  = (const float*)d_in[2];
  const float* ew2  = (const float*)d_in[3];
  const float* eb2  = (const float*)d_in[4];
  const float* ew3  = (const float*)d_in[5];
  const float* eb3  = (const float*)d_in[6];
  const float* gwi  = (const float*)d_in[7];
  const float* gbi  = (const float*)d_in[8];
  const float* gwh  = (const float*)d_in[9];
  const float* gbhn = (const float*)d_in[10];
  const float* pw1  = (const float*)d_in[11];
  const float* pb1  = (const float*)d_in[12];
  const float* pw2  = (const float*)d_in[13];
  const float* pb2  = (const float*)d_in[14];

  char* W = (char*)d_ws;
  u32*   flags = (u32*)(W + 64);        // [16] per-role step flags
  float* lacc = (float*)(W + 2048);
  u16*   w1T  = (u16*)(W + 4096);
  u16*   w2T  = (u16*)(W + 135168);
  u16*   w3T  = (u16*)(W + 659456);
  u16*   wiT  = (u16*)(W + 921600);
  u16*   p1T  = (u16*)(W + 1708032);
  u16*   p2T  = (u16*)(W + 2232320);
  u16*   hbuf = (u16*)(W + 2494464);
  float* diag = (float*)(W + 2527232);
  u16*   zhat = (u16*)(W + 2911232);
  u16*   zbf  = (u16*)(W + 7105536);    // g3 out, dead after g4
  u16*   cbf  = (u16*)(W + 7105536);    // gru out (after zbf dead)
  u16*   ppk  = (u16*)(W + 7105536);    // norm2 out (after cbf dead)
  u16*   xi   = (u16*)(W + 15494144);
  u16*   xbf  = (u16*)(W + 15494144);   // alias (dead before xi written)
  u16*   h1   = (u16*)(W + 17591296);   // alias
  u16*   h2   = (u16*)(W + 25979904);   // alias
  float* g    = (float*)(W + 15494144); // alias (xi dead after gru)

  float* zf    = (float*)d_out;
  float* cf    = zf + 2097152;
  float* lout  = zf + 6291456;

  hipMemsetAsync(d_ws, 0, 4096, stream);    // zero flags + lacc

  cvt_k<<<1024, 256, 0, stream>>>((const float4*)x, (ushort4*)xbf);

  dim3 tb(32, 8);
  tr_k<<<dim3(16, 4),  tb, 0, stream>>>(ew1, w1T, 128, 512);
  tr_k<<<dim3(16, 16), tb, 0, stream>>>(ew2, w2T, 512, 512);
  tr_k<<<dim3(8, 16),  tb, 0, stream>>>(ew3, w3T, 512, 256);
  tr_k<<<dim3(48, 8),  tb, 0, stream>>>(gwi, wiT, 256, 1536);
  tr_k<<<dim3(16, 16), tb, 0, stream>>>(pw1, p1T, 512, 512);
  tr_k<<<dim3(8, 16),  tb, 0, stream>>>(pw2, p2T, 512, 256);

  gemm_k<<<dim3(4, 64),  256, 0, stream>>>(xbf,  w1T, eb1, h1,  nullptr, 512, 128, 1);
  gemm_k<<<dim3(4, 64),  256, 0, stream>>>(h1,   w2T, eb2, h2,  nullptr, 512, 512, 1);
  gemm_k<<<dim3(2, 64),  256, 0, stream>>>(h2,   w3T, eb3, zbf, zf,      256, 512, 0);
  norm_k<<<2048, 256, 0, stream>>>(zbf, zhat, 0);
  gemm_k<<<dim3(12, 64), 256, 0, stream>>>(zbf,  wiT, gbi, xi,  nullptr, 1536, 256, 0);
  gru_k<<<16, 512, 0, stream>>>(xi, gwh, gbhn, cf, cbf, hbuf, flags);
  gemm_k<<<dim3(4, 64),  256, 0, stream>>>(cbf,  p1T, pb1, h1,  nullptr, 512, 512, 1);
  gemm_k<<<dim3(2, 64),  256, 0, stream>>>(h1,   p2T, pb2, h2,  nullptr, 256, 512, 0);
  norm_k<<<2048, 256, 0, stream>>>(h2, ppk, 1);
  sgemm_k<<<dim3(4, 63), 256, 0, stream>>>(ppk, zhat, g, diag);
  win_k<<<2000, 256, 0, stream>>>(g, diag, lacc);
  fin_k<<<1, 1, 0, stream>>>(lacc, lout);
}

// Round 9
// 1886.077 us; speedup vs baseline: 1.1866x; 1.0141x over previous
//
#include <hip/hip_runtime.h>
#include <cstdint>
#include <cstddef>

typedef unsigned short u16;
typedef unsigned int   u32;
typedef unsigned long long u64;
typedef __attribute__((ext_vector_type(8))) short bf16x8;   // 8 bf16 = 4 VGPRs
typedef __attribute__((ext_vector_type(4))) float f32x4;
typedef __attribute__((ext_vector_type(4))) unsigned int u32x4;

typedef __attribute__((address_space(1))) const unsigned int as1c_uint;
typedef __attribute__((address_space(3))) unsigned int as3_uint;

__device__ __forceinline__ void async16(const void* g, void* l) {
  __builtin_amdgcn_global_load_lds((as1c_uint*)g, (as3_uint*)l, 16, 0, 0);
}
__device__ __forceinline__ float bf2f(u16 u) {
  return __uint_as_float(((u32)u) << 16);
}
__device__ __forceinline__ u16 f2bf(float x) {
  u32 u = __float_as_uint(x);
  u32 r = u + 0x7FFFu + ((u >> 16) & 1u);
  return (u16)(r >> 16);
}

// LDS-only barrier: orders LDS ops without draining vmcnt (in-flight global
// prefetch loads / output stores survive the barrier).
__device__ __forceinline__ void bar_lds() {
  asm volatile("s_waitcnt lgkmcnt(0)" ::: "memory");
  __builtin_amdgcn_s_barrier();
  asm volatile("" ::: "memory");
}

// ---- IC-scope ops (sc0 sc1: bypass L1+L2, serviced at Infinity Cache — the
// ONLY cross-WG coherence point usable here; XCD-local sc0 exchange was tried
// twice (r6/r7) and is stale-L1-broken on gfx950). Round-0 protocol, measured
// 1462us: publisher h-store(IC) -> vmcnt(0) ack -> barrier -> flag-store(IC);
// readers poll one packed flag line then wide-load the h slice. ----
__device__ __forceinline__ u32 ld_u32_ic(const void* p) {
  u32 v;
  asm volatile("global_load_dword %0, %1, off sc0 sc1\n\ts_waitcnt vmcnt(0)"
               : "=v"(v) : "v"(p) : "memory");
  return v;
}
__device__ __forceinline__ void st_u32_ic(void* p, u32 v) {
  asm volatile("global_store_dword %0, %1, off sc0 sc1" :: "v"(p), "v"(v) : "memory");
}
__device__ __forceinline__ void ld_h64_ic(const void* p, u32x4& a, u32x4& b,
                                          u32x4& c, u32x4& d) {
  asm volatile(
      "global_load_dwordx4 %0, %4, off sc0 sc1\n\t"
      "global_load_dwordx4 %1, %4, off offset:16 sc0 sc1\n\t"
      "global_load_dwordx4 %2, %4, off offset:32 sc0 sc1\n\t"
      "global_load_dwordx4 %3, %4, off offset:48 sc0 sc1\n\t"
      "s_waitcnt vmcnt(0)"
      : "=&v"(a), "=&v"(b), "=&v"(c), "=&v"(d) : "v"(p) : "memory");
}

// ---------------- fused prep: fp32->bf16 convert (x) + 6 weight transposes ----------
// One launch replaces cvt_k + 6 tr_k (saves 6 launch gaps; small transposes run
// concurrently). Block ranges are compile-time; each block takes one uniform path.
__global__ __launch_bounds__(256) void prep_k(
    const float* __restrict__ x, u16* __restrict__ xbf,
    const float* __restrict__ ew1, u16* __restrict__ w1T,
    const float* __restrict__ ew2, u16* __restrict__ w2T,
    const float* __restrict__ ew3, u16* __restrict__ w3T,
    const float* __restrict__ gwi, u16* __restrict__ wiT,
    const float* __restrict__ pw1, u16* __restrict__ p1T,
    const float* __restrict__ pw2, u16* __restrict__ p2T) {
  int b = blockIdx.x;
  int tid = threadIdx.x;
  if (b < 1024) {                        // cvt: 1024 blocks x 256 float4
    int i = b * 256 + tid;
    float4 v = ((const float4*)x)[i];
    ushort4 o;
    o.x = f2bf(v.x); o.y = f2bf(v.y); o.z = f2bf(v.z); o.w = f2bf(v.w);
    ((ushort4*)xbf)[i] = o;
    return;
  }
  b -= 1024;
  const float* in; u16* out; int K, N, gx, idx;
  if      (b <   64) { in = ew1; out = w1T; K = 128; N =  512; gx = 16; idx = b;        }
  else if (b <  320) { in = ew2; out = w2T; K = 512; N =  512; gx = 16; idx = b -   64; }
  else if (b <  448) { in = ew3; out = w3T; K = 512; N =  256; gx =  8; idx = b -  320; }
  else if (b <  832) { in = gwi; out = wiT; K = 256; N = 1536; gx = 48; idx = b -  448; }
  else if (b < 1088) { in = pw1; out = p1T; K = 512; N =  512; gx = 16; idx = b -  832; }
  else               { in = pw2; out = p2T; K = 512; N =  256; gx =  8; idx = b - 1088; }
  int bx = idx % gx, by = idx / gx;
  __shared__ u16 t[32][33];
  int bn = bx * 32, bk = by * 32;
  int x_ = tid & 31, y = tid >> 5;
#pragma unroll
  for (int i = 0; i < 32; i += 8)
    t[y + i][x_] = f2bf(in[(size_t)(bk + y + i) * N + bn + x_]);
  __syncthreads();
#pragma unroll
  for (int i = 0; i < 32; i += 8)
    out[(size_t)(bn + y + i) * K + bk + x_] = t[x_][y + i];
}

// ---------------- generic GEMM: C[M,N] = act(A[M,K] @ Bt[N,K]^T + bias) --------------
// Double-buffered LDS staging: issue next K-tile, compute current, ONE barrier
// per K-step (__syncthreads drains vmcnt, so the just-issued global_load_lds of
// the next tile completes under the current tile's MFMA).
__global__ __launch_bounds__(256) void gemm_k(
    const u16* __restrict__ A, const u16* __restrict__ Bt,
    const float* __restrict__ bias, u16* __restrict__ Cbf, float* __restrict__ Cf,
    int N, int K, int act) {
  __shared__ __align__(16) u16 As[2][128 * 32];
  __shared__ __align__(16) u16 Bs[2][128 * 32];
  int tid = threadIdx.x;
  int lane = tid & 63, w = tid >> 6;
  int wm = w >> 1, wn = w & 1;
  int mm = lane & 15, kh = lane >> 4;
  int m0 = blockIdx.y * 128, n0 = blockIdx.x * 128;

  f32x4 zero = {0.f, 0.f, 0.f, 0.f};
  f32x4 acc[4][4];
#pragma unroll
  for (int i = 0; i < 4; ++i)
#pragma unroll
    for (int j = 0; j < 4; ++j) acc[i][j] = zero;

  int row0 = tid >> 2, kc0 = (tid & 3) * 8;
  int row1 = (tid + 256) >> 2, kc1 = ((tid + 256) & 3) * 8;

  // prologue: stage kt=0 into buffer 0
  async16(A  + (size_t)(m0 + row0) * K + kc0, &As[0][tid * 8]);
  async16(Bt + (size_t)(n0 + row0) * K + kc0, &Bs[0][tid * 8]);
  async16(A  + (size_t)(m0 + row1) * K + kc1, &As[0][(tid + 256) * 8]);
  async16(Bt + (size_t)(n0 + row1) * K + kc1, &Bs[0][(tid + 256) * 8]);
  __syncthreads();

  int nk = K >> 5;
  for (int ki = 0; ki < nk; ++ki) {
    int cur = ki & 1, nxt = cur ^ 1;
    if (ki + 1 < nk) {
      int kt = (ki + 1) * 32;
      async16(A  + (size_t)(m0 + row0) * K + kt + kc0, &As[nxt][tid * 8]);
      async16(Bt + (size_t)(n0 + row0) * K + kt + kc0, &Bs[nxt][tid * 8]);
      async16(A  + (size_t)(m0 + row1) * K + kt + kc1, &As[nxt][(tid + 256) * 8]);
      async16(Bt + (size_t)(n0 + row1) * K + kt + kc1, &Bs[nxt][(tid + 256) * 8]);
    }
    bf16x8 av[4], bv[4];
#pragma unroll
    for (int i = 0; i < 4; ++i) {
      av[i] = *(const bf16x8*)&As[cur][(wm * 64 + i * 16 + mm) * 32 + kh * 8];
      bv[i] = *(const bf16x8*)&Bs[cur][(wn * 64 + i * 16 + mm) * 32 + kh * 8];
    }
#pragma unroll
    for (int im = 0; im < 4; ++im)
#pragma unroll
      for (int in = 0; in < 4; ++in)
        acc[im][in] = __builtin_amdgcn_mfma_f32_16x16x32_bf16(av[im], bv[in], acc[im][in], 0, 0, 0);
    __syncthreads();   // drains vmcnt (next tile staged) + everyone done reading cur
  }

#pragma unroll
  for (int im = 0; im < 4; ++im)
#pragma unroll
    for (int in = 0; in < 4; ++in)
#pragma unroll
      for (int r = 0; r < 4; ++r) {
        int gm = m0 + wm * 64 + im * 16 + kh * 4 + r;
        int gn = n0 + wn * 64 + in * 16 + mm;
        float v = acc[im][in][r] + bias[gn];
        if (act) v = fmaxf(v, 0.f);
        size_t off = (size_t)gm * N + gn;
        if (Cbf) Cbf[off] = f2bf(v);
        if (Cf)  Cf[off]  = v;
      }
}

// ---------------- row L2-normalize [rows,256] bf16 -> bf16 (optional pack t<500) ------
__global__ __launch_bounds__(256) void norm_k(const u16* __restrict__ in,
                                              u16* __restrict__ out, int pack) {
  int row = blockIdx.x * 4 + (threadIdx.x >> 6);
  int lane = threadIdx.x & 63;
  ushort4 v = ((const ushort4*)(in + (size_t)row * 256))[lane];
  float a = bf2f(v.x), b = bf2f(v.y), c = bf2f(v.z), d = bf2f(v.w);
  float s = a * a + b * b + c * c + d * d;
#pragma unroll
  for (int o = 32; o; o >>= 1) s += __shfl_xor(s, o);
  float rn = rsqrtf(s);
  int orow = row;
  if (pack) {
    int bb = row >> 9, tt = row & 511;
    if (tt >= 500) return;
    orow = bb * 500 + tt;
  }
  ushort4 o4;
  o4.x = f2bf(a * rn); o4.y = f2bf(b * rn);
  o4.z = f2bf(c * rn); o4.w = f2bf(d * rn);
  *(ushort4*)(out + (size_t)orow * 256 + lane * 4) = o4;
}

// ---------------- persistent GRU: 16 WGs, exchange at Infinity Cache -----------------
// VERBATIM the measured-1462us r5 kernel. Flag protocol (publisher h-store(IC)
// -> vmcnt(0) -> flag-store; readers poll one flag line then wide-load the h
// slice) + LDS-only barriers. Waves 0-3: h exchange + combine; 0-5: MFMA;
// 6-7: xi prefetch (2-deep) + cf/cbf outputs (1-step delayed).
#define HS 520

__global__ __launch_bounds__(512, 1) void gru_k(
    const u16* __restrict__ xi, const float* __restrict__ WH,
    const float* __restrict__ BHN, float* __restrict__ cf,
    u16* __restrict__ cbf, u16* hbuf, u32* flags) {
  __shared__ __align__(16) u16 hs[16 * HS];
  __shared__ float xis[2 * 1536];
  __shared__ float gts[1536];
  __shared__ float hnf[512];

  int tid = threadIdx.x;
  int role = blockIdx.x;                   // 0..15
  int c0 = role * 32;

  int lane = tid & 63, w = tid >> 6;
  int mm = lane & 15, kh = lane >> 4;

  // persistent B-fragments (waves 0-5): gate cols {r,u,n} x 16, k-major
  bf16x8 wf[16];
  if (w < 6) {
    int gcol = (w >> 1) * 512 + c0 + (w & 1) * 16 + mm;
    int kb = kh * 8;
#pragma unroll
    for (int kk = 0; kk < 16; ++kk) {
      bf16x8 tf;
#pragma unroll
      for (int j = 0; j < 8; ++j)
        tf[j] = (short)f2bf(WH[(size_t)(kk * 32 + kb + j) * 1536 + gcol]);
      wf[kk] = tf;
    }
  }
  // combine constants (waves 0-3: 2 adjacent cols per thread)
  int cr = tid >> 4, cj = (tid & 15) * 2;
  float bhn0 = 0.f, bhn1 = 0.f;
  if (w < 4) { bhn0 = BHN[c0 + cj]; bhn1 = BHN[c0 + cj + 1]; }

  // xi pipeline (waves 6-7): 12 values/thread/step, 2-step prefetch
  int tt = tid - 384;
  size_t xoff[12];
  u16 xpre[12];
  if (w >= 6) {
#pragma unroll
    for (int j = 0; j < 12; ++j) {
      int v = j * 128 + tt;
      int b = v / 96, q = v - b * 96;
      int gcol = (q >> 5) * 512 + c0 + (q & 31);
      xoff[j] = (size_t)b * 512 * 1536 + gcol;
      xis[v] = bf2f(xi[xoff[j]]);                 // xi(t=0) -> slot 0
    }
#pragma unroll
    for (int j = 0; j < 12; ++j) xpre[j] = xi[xoff[j] + 1536];   // issue xi(1)
  }

  for (int t = 0; t < 512; ++t) {
    // ---- phase A ----
    if (w < 4) {                       // h staging via IC (clean vmcnt path)
      if (t == 0) {
        for (int i = tid; i < 16 * HS; i += 256) hs[i] = 0;
      } else {
        int iter = 0;
        const u32* fl = &flags[tid & 15];
        while (ld_u32_ic(fl) < (u32)t) { if (++iter > (1 << 20)) break; }
        const u16* hb = hbuf + (size_t)(t & 1) * 8192 + (tid >> 4) * 512 + (tid & 15) * 32;
        u32x4 a, b, c, d;
        ld_h64_ic(hb, a, b, c, d);
        u32x4* dst = (u32x4*)&hs[(tid >> 4) * HS + (tid & 15) * 32];
        dst[0] = a; dst[1] = b; dst[2] = c; dst[3] = d;
      }
    } else if (w >= 6) {               // outputs(t-1) + xi pipeline (own vmcnt)
      if (t > 0) {
        int v = tt * 4;
        int b = v >> 5, col = v & 31;
        size_t co = ((size_t)b * 512 + (t - 1)) * 512 + c0 + col;
        float4 o;
        o.x = hnf[v]; o.y = hnf[v + 1]; o.z = hnf[v + 2]; o.w = hnf[v + 3];
        *(float4*)&cf[co] = o;
        uint2 pk;
        pk.x = (u32)f2bf(o.x) | ((u32)f2bf(o.y) << 16);
        pk.y = (u32)f2bf(o.z) | ((u32)f2bf(o.w) << 16);
        *(uint2*)&cbf[co] = pk;
      }
      if (t < 511) {
        float* xd = &xis[((t + 1) & 1) * 1536];
#pragma unroll
        for (int j = 0; j < 12; ++j) xd[j * 128 + tt] = bf2f(xpre[j]);
      }
      if (t < 510) {
        const u16* xs = xi + (size_t)(t + 2) * 1536;
#pragma unroll
        for (int j = 0; j < 12; ++j) xpre[j] = xs[xoff[j]];
      }
    }
    bar_lds();

    // ---- phase B: hp = h @ WH[:, my 16 gate cols] ----
    if (w < 6) {
      f32x4 acc = {0.f, 0.f, 0.f, 0.f};
#pragma unroll
      for (int kk = 0; kk < 16; ++kk) {
        bf16x8 a = *(const bf16x8*)&hs[mm * HS + kk * 32 + kh * 8];
        acc = __builtin_amdgcn_mfma_f32_16x16x32_bf16(a, wf[kk], acc, 0, 0, 0);
      }
      int gc = (w >> 1) * 32 + (w & 1) * 16 + mm;
#pragma unroll
      for (int r = 0; r < 4; ++r) gts[(kh * 4 + r) * 96 + gc] = acc[r];
    }
    bar_lds();

    // ---- phase C: combine (waves 0-3, 2 cols/thread); publish h(IC); ack; flag ----
    if (w < 4) {
      const float* xc = &xis[(t & 1) * 1536] + cr * 96;
      const float* gr_ = &gts[cr * 96];
      float hp0 = bf2f(hs[cr * HS + c0 + cj]);
      float hp1 = bf2f(hs[cr * HS + c0 + cj + 1]);
      float r0 = 1.f / (1.f + __expf(-(xc[cj] + gr_[cj])));
      float u0 = 1.f / (1.f + __expf(-(xc[32 + cj] + gr_[32 + cj])));
      float nx0 = xc[64 + cj] + r0 * (gr_[64 + cj] + bhn0);
      float n0 = 1.f - 2.f / (__expf(2.f * nx0) + 1.f);
      float h0 = (1.f - u0) * n0 + u0 * hp0;
      float r1 = 1.f / (1.f + __expf(-(xc[cj + 1] + gr_[cj + 1])));
      float u1 = 1.f / (1.f + __expf(-(xc[33 + cj] + gr_[33 + cj])));
      float nx1 = xc[65 + cj] + r1 * (gr_[65 + cj] + bhn1);
      float n1 = 1.f - 2.f / (__expf(2.f * nx1) + 1.f);
      float h1v = (1.f - u1) * n1 + u1 * hp1;
      hnf[cr * 32 + cj] = h0;
      hnf[cr * 32 + cj + 1] = h1v;
      u32 pk = (u32)f2bf(h0) | ((u32)f2bf(h1v) << 16);
      st_u32_ic(hbuf + (size_t)((t + 1) & 1) * 8192 + cr * 512 + c0 + cj, pk);
      asm volatile("s_waitcnt vmcnt(0)" ::: "memory");   // h at IC before flag
    }
    bar_lds();
    if (tid == 0) st_u32_ic(&flags[role], (u32)(t + 1));
  }

  // epilogue: outputs for t=511
  if (w >= 6) {
    int v = tt * 4;
    int b = v >> 5, col = v & 31;
    size_t co = ((size_t)b * 512 + 511) * 512 + c0 + col;
    float4 o;
    o.x = hnf[v]; o.y = hnf[v + 1]; o.z = hnf[v + 2]; o.w = hnf[v + 3];
    *(float4*)&cf[co] = o;
    uint2 pk;
    pk.x = (u32)f2bf(o.x) | ((u32)f2bf(o.y) << 16);
    pk.y = (u32)f2bf(o.z) | ((u32)f2bf(o.w) << 16);
    *(uint2*)&cbf[co] = pk;
  }
}

// ---------------- S = p . zhat^T fused with exp/g-reduction + diag capture -----------
// Bs double-buffered: stage (b,kk)+1 while computing (b,kk); one barrier per
// inner iteration instead of two.
__global__ __launch_bounds__(256) void sgemm_k(
    const u16* __restrict__ P, const u16* __restrict__ Z,
    float* __restrict__ g, float* __restrict__ diag) {
  __shared__ __align__(16) u16 Ap[128 * 256];
  __shared__ __align__(16) u16 Bs[2][128 * 32];
  __shared__ float gacc[128 * 128];
  int tid = threadIdx.x;
  int lane = tid & 63, w = tid >> 6;
  int wm = w >> 1, wn = w & 1;
  int mm = lane & 15, kh = lane >> 4;
  int r0 = blockIdx.y * 128, t0 = blockIdx.x * 128;

  int zrow0 = tid >> 2, zkc0 = (tid & 3) * 8;
  int zrow1 = (tid + 256) >> 2, zkc1 = ((tid + 256) & 3) * 8;

#pragma unroll
  for (int it = 0; it < 16; ++it) {
    int q = tid + it * 256;
    int row = q >> 5, kc = (q & 31) * 8;
    async16(P + (size_t)(r0 + row) * 256 + kc, &Ap[q * 8]);
  }
  // prologue: stage (b=0, kk=0) into Bs[0]
  async16(Z + (size_t)(t0 + zrow0) * 256 + zkc0, &Bs[0][tid * 8]);
  async16(Z + (size_t)(t0 + zrow1) * 256 + zkc1, &Bs[0][(tid + 256) * 8]);
  for (int i = tid; i < 128 * 128; i += 256) gacc[i] = 0.f;
  __syncthreads();

  f32x4 zero = {0.f, 0.f, 0.f, 0.f};
  for (int b = 0; b < 16; ++b) {
    int n0 = b * 512 + t0;
    f32x4 acc[4][4];
#pragma unroll
    for (int i = 0; i < 4; ++i)
#pragma unroll
      for (int j = 0; j < 4; ++j) acc[i][j] = zero;

    for (int kk = 0; kk < 8; ++kk) {
      int it = b * 8 + kk, cur = it & 1;
      if (it + 1 < 128) {
        int nb = (it + 1) >> 3, nkk = (it + 1) & 7;
        int nn0 = nb * 512 + t0;
        async16(Z + (size_t)(nn0 + zrow0) * 256 + nkk * 32 + zkc0, &Bs[cur ^ 1][tid * 8]);
        async16(Z + (size_t)(nn0 + zrow1) * 256 + nkk * 32 + zkc1, &Bs[cur ^ 1][(tid + 256) * 8]);
      }
      bf16x8 av[4], bv[4];
#pragma unroll
      for (int i = 0; i < 4; ++i) {
        av[i] = *(const bf16x8*)&Ap[(wm * 64 + i * 16 + mm) * 256 + kk * 32 + kh * 8];
        bv[i] = *(const bf16x8*)&Bs[cur][(wn * 64 + i * 16 + mm) * 32 + kh * 8];
      }
#pragma unroll
      for (int im = 0; im < 4; ++im)
#pragma unroll
        for (int in = 0; in < 4; ++in)
          acc[im][in] = __builtin_amdgcn_mfma_f32_16x16x32_bf16(av[im], bv[in], acc[im][in], 0, 0, 0);
      __syncthreads();   // next staged + everyone done with cur
    }
#pragma unroll
    for (int im = 0; im < 4; ++im)
#pragma unroll
      for (int in = 0; in < 4; ++in)
#pragma unroll
        for (int r = 0; r < 4; ++r) {
          int row = wm * 64 + im * 16 + kh * 4 + r;
          int col = wn * 64 + in * 16 + mm;
          float s10 = acc[im][in][r] * 10.f;
          gacc[row * 128 + col] += __expf(s10 - 10.f);
          int ig = r0 + row;
          if (ig < 8000) {
            int bi = ig / 500;
            if (bi == b) {
              int ti = ig - bi * 500;
              int dt = t0 + col - ti;
              if (dt >= 1 && dt <= 12) diag[(size_t)ig * 12 + dt - 1] = s10;
            }
          }
        }
  }
  __syncthreads();
  for (int i = tid; i < 128 * 128; i += 256) {
    int row = i >> 7, col = i & 127;
    g[(size_t)(r0 + row) * 512 + t0 + col] = gacc[i];
  }
}

// ---------------- window logsumexp + loss partial sums (one wave per row) ------------
__global__ __launch_bounds__(256) void win_k(const float* __restrict__ g,
                                             const float* __restrict__ diag,
                                             float* __restrict__ acc) {
  __shared__ float lo[4][16], hi[4][16];
  int w = threadIdx.x >> 6, lane = threadIdx.x & 63;
  int row = blockIdx.x * 4 + w;
  const float* gr = g + (size_t)row * 512;
  float4 a = ((const float4*)gr)[lane * 2];
  float4 b = ((const float4*)gr)[lane * 2 + 1];
  float s = a.x + a.y + a.z + a.w + b.x + b.y + b.z + b.w;
#pragma unroll
  for (int o = 32; o; o >>= 1) s += __shfl_xor(s, o);
  if (lane == 0) { lo[w][0]=a.x; lo[w][1]=a.y; lo[w][2]=a.z; lo[w][3]=a.w;
                   lo[w][4]=b.x; lo[w][5]=b.y; lo[w][6]=b.z; lo[w][7]=b.w; }
  if (lane == 1) { lo[w][8]=a.x; lo[w][9]=a.y; lo[w][10]=a.z; lo[w][11]=a.w; }
  if (lane == 62){ hi[w][0]=b.x; hi[w][1]=b.y; hi[w][2]=b.z; hi[w][3]=b.w; }
  if (lane == 63){ hi[w][4]=a.x; hi[w][5]=a.y; hi[w][6]=a.z; hi[w][7]=a.w;
                   hi[w][8]=b.x; hi[w][9]=b.y; hi[w][10]=b.z; hi[w][11]=b.w; }
  __syncthreads();
  float term = 0.f;
  if (lane < 12) {
    int k = lane + 1;
    float pre = 0.f, suf = 0.f;
#pragma unroll
    for (int j = 0; j < 12; ++j) {
      if (j < k) pre += lo[w][j];
      if (j >= k) suf += hi[w][j];
    }
    float W = s - pre - suf;
    term = diag[(size_t)row * 12 + lane] - __logf(W) - 10.f;
  }
#pragma unroll
  for (int o = 32; o; o >>= 1) term += __shfl_xor(term, o);
  if (lane == 0) atomicAdd(acc, term);
}

__global__ void fin_k(const float* acc, float* lout) {
  lout[0] = -acc[0] * (1.f / 96000.f);
}

// ============================== launch ==============================
extern "C" void kernel_launch(void* const* d_in, const int* in_sizes, int n_in,
                              void* d_out, int out_size, void* d_ws, size_t ws_size,
                              hipStream_t stream) {
  (void)in_sizes; (void)n_in; (void)out_size; (void)ws_size;
  const float* x    = (const float*)d_in[0];
  const float* ew1  = (const float*)d_in[1];
  const float* eb1  = (const float*)d_in[2];
  const float* ew2  = (const float*)d_in[3];
  const float* eb2  = (const float*)d_in[4];
  const float* ew3  = (const float*)d_in[5];
  const float* eb3  = (const float*)d_in[6];
  const float* gwi  = (const float*)d_in[7];
  const float* gbi  = (const float*)d_in[8];
  const float* gwh  = (const float*)d_in[9];
  const float* gbhn = (const float*)d_in[10];
  const float* pw1  = (const float*)d_in[11];
  const float* pb1  = (const float*)d_in[12];
  const float* pw2  = (const float*)d_in[13];
  const float* pb2  = (const float*)d_in[14];

  char* W = (char*)d_ws;
  u32*   flags = (u32*)(W + 64);        // [16] per-role step flags
  float* lacc = (float*)(W + 2048);
  u16*   w1T  = (u16*)(W + 4096);
  u16*   w2T  = (u16*)(W + 135168);
  u16*   w3T  = (u16*)(W + 659456);
  u16*   wiT  = (u16*)(W + 921600);
  u16*   p1T  = (u16*)(W + 1708032);
  u16*   p2T  = (u16*)(W + 2232320);
  u16*   hbuf = (u16*)(W + 2494464);
  float* diag = (float*)(W + 2527232);
  u16*   zhat = (u16*)(W + 2911232);
  u16*   zbf  = (u16*)(W + 7105536);    // g3 out, dead after g4
  u16*   cbf  = (u16*)(W + 7105536);    // gru out (after zbf dead)
  u16*   ppk  = (u16*)(W + 7105536);    // norm2 out (after cbf dead)
  u16*   xi   = (u16*)(W + 15494144);
  u16*   xbf  = (u16*)(W + 15494144);   // alias (dead before xi written)
  u16*   h1   = (u16*)(W + 17591296);   // alias
  u16*   h2   = (u16*)(W + 25979904);   // alias
  float* g    = (float*)(W + 15494144); // alias (xi dead after gru)

  float* zf    = (float*)d_out;
  float* cf    = zf + 2097152;
  float* lout  = zf + 6291456;

  hipMemsetAsync(d_ws, 0, 4096, stream);    // zero flags + lacc

  prep_k<<<2240, 256, 0, stream>>>(x, xbf, ew1, w1T, ew2, w2T, ew3, w3T,
                                   gwi, wiT, pw1, p1T, pw2, p2T);

  gemm_k<<<dim3(4, 64),  256, 0, stream>>>(xbf,  w1T, eb1, h1,  nullptr, 512, 128, 1);
  gemm_k<<<dim3(4, 64),  256, 0, stream>>>(h1,   w2T, eb2, h2,  nullptr, 512, 512, 1);
  gemm_k<<<dim3(2, 64),  256, 0, stream>>>(h2,   w3T, eb3, zbf, zf,      256, 512, 0);
  norm_k<<<2048, 256, 0, stream>>>(zbf, zhat, 0);
  gemm_k<<<dim3(12, 64), 256, 0, stream>>>(zbf,  wiT, gbi, xi,  nullptr, 1536, 256, 0);
  gru_k<<<16, 512, 0, stream>>>(xi, gwh, gbhn, cf, cbf, hbuf, flags);
  gemm_k<<<dim3(4, 64),  256, 0, stream>>>(cbf,  p1T, pb1, h1,  nullptr, 512, 512, 1);
  gemm_k<<<dim3(2, 64),  256, 0, stream>>>(h1,   p2T, pb2, h2,  nullptr, 256, 512, 0);
  norm_k<<<2048, 256, 0, stream>>>(h2, ppk, 1);
  sgemm_k<<<dim3(4, 63), 256, 0, stream>>>(ppk, zhat, g, diag);
  win_k<<<2000, 256, 0, stream>>>(g, diag, lacc);
  fin_k<<<1, 1, 0, stream>>>(lacc, lout);
}